// Round 1
// baseline (8670.571 us; speedup 1.0000x reference)
//
#include <hip/hip_runtime.h>
#include <cstdint>
#include <cstddef>

#define H    500
#define G3   1500
#define SEQ  512
#define V    50000
#define NT   391          // ceil(50000/128)

#define NB   25           // GRU worker workgroups; HSL = 20 h-elements per WG
#define HSL  20
#define ROWS 60           // 3 gates x 20 rows per WG
#define NWG_LAUNCH 256    // oversubscribe so some XCD is guaranteed >= NB WGs

// ---------------- workspace layout (bytes) ----------------
static constexpr size_t OFS_HBUF_E = 0;            // [2 bufs][25 slices][32 u64]
static constexpr size_t OFS_CLAIM  = 32768;        // 9 ints: cnt[8] + winner
static constexpr size_t OFS_GI_ENC = 65536;        // 512*1500 f32
static constexpr size_t OFS_GI_DEC = OFS_GI_ENC + 3276800;
static constexpr size_t OFS_DECHS  = OFS_GI_DEC + 3276800;   // 512*500 f32
static constexpr size_t OFS_SPART  = OFS_DECHS + 1048576;    // 512*NT f32
static constexpr size_t OFS_PPART  = OFS_SPART + 1048576;    // 512*NT u64
static constexpr size_t OFS_LTGT   = OFS_PPART + 2097152;    // 512 f32
static constexpr size_t OFS_SFIN   = OFS_LTGT + 4096;        // 512 f32

// ---------------- L2-coherent (same-XCD) access helpers ----------------
// sc0 = legacy glc: bypass per-CU L1, coherent at the XCD's L2.
typedef unsigned int u32x4 __attribute__((ext_vector_type(4)));

__device__ __forceinline__ u32x4 ld16_sc0(const unsigned long long* p) {
    u32x4 r;
    asm volatile("global_load_dwordx4 %0, %1, off sc0\n\ts_waitcnt vmcnt(0)"
                 : "=v"(r) : "v"(p) : "memory");
    return r;
}
__device__ __forceinline__ void st8_sc0(unsigned long long* p, unsigned long long v) {
    asm volatile("global_store_dwordx2 %0, %1, off sc0"
                 :: "v"(p), "v"(v) : "memory");
}

// ---------------- input-gate GEMM: Gi = gather(emb)@Wih.T + bih (enc z=0, dec z=1) ----------------
#define GI_BM 64
#define GI_BN 64
#define GI_BK 20
__global__ __launch_bounds__(256) void k_gi_gemm(
    const float* __restrict__ eA, const float* __restrict__ WA,
    const float* __restrict__ bA, const int* __restrict__ tA,
    const float* __restrict__ eB, const float* __restrict__ WB,
    const float* __restrict__ bB, const int* __restrict__ tB,
    float* __restrict__ GiA, float* __restrict__ GiB,
    int* __restrict__ claim)
{
    // reset the XCD-claim state for the GRU kernel that follows on this stream
    if (blockIdx.x == 0 && blockIdx.y == 0 && blockIdx.z == 0 && threadIdx.x < 16)
        claim[threadIdx.x] = (threadIdx.x == 8) ? -1 : 0;

    const int dec = blockIdx.z;
    const float* emb = dec ? eB : eA;
    const float* Wih = dec ? WB : WA;
    const float* bih = dec ? bB : bA;
    const int*  toks = dec ? tB : tA;
    float* Gi        = dec ? GiB : GiA;

    __shared__ __align__(16) float As[GI_BK * GI_BM];
    __shared__ __align__(16) float Bs[GI_BK * GI_BN];
    const int tid = threadIdx.x;
    const int n0 = blockIdx.x * GI_BN;
    const int m0 = blockIdx.y * GI_BM;
    const int tx = tid & 15, ty = tid >> 4;
    float acc[4][4] = {};
    for (int k0 = 0; k0 < H; k0 += GI_BK) {
        for (int x = tid; x < 320; x += 256) {        // 64 rows x 5 float4
            int m = x / 5, kq = x - m * 5;
            int gm = m0 + m;
            int tok = dec ? ((gm == 0) ? 0 : toks[gm - 1]) : toks[gm];
            float4 v = *(const float4*)(emb + (size_t)tok * H + k0 + kq * 4);
            if (dec) { v.x = fmaxf(v.x, 0.f); v.y = fmaxf(v.y, 0.f);
                       v.z = fmaxf(v.z, 0.f); v.w = fmaxf(v.w, 0.f); }
            int kb = kq * 4;
            As[(kb + 0) * GI_BM + m] = v.x; As[(kb + 1) * GI_BM + m] = v.y;
            As[(kb + 2) * GI_BM + m] = v.z; As[(kb + 3) * GI_BM + m] = v.w;
        }
        for (int x = tid; x < 320; x += 256) {
            int n = x / 5, kq = x - n * 5;
            int gn = n0 + n;
            float4 v = make_float4(0.f, 0.f, 0.f, 0.f);
            if (gn < G3) v = *(const float4*)(Wih + (size_t)gn * H + k0 + kq * 4);
            int kb = kq * 4;
            Bs[(kb + 0) * GI_BN + n] = v.x; Bs[(kb + 1) * GI_BN + n] = v.y;
            Bs[(kb + 2) * GI_BN + n] = v.z; Bs[(kb + 3) * GI_BN + n] = v.w;
        }
        __syncthreads();
#pragma unroll 5
        for (int kk = 0; kk < GI_BK; ++kk) {
            float a[4], b[4];
            *(float4*)&a[0] = *(const float4*)&As[kk * GI_BM + ty * 4];
            *(float4*)&b[0] = *(const float4*)&Bs[kk * GI_BN + tx * 4];
#pragma unroll
            for (int i = 0; i < 4; i++)
#pragma unroll
                for (int j = 0; j < 4; j++) acc[i][j] = fmaf(a[i], b[j], acc[i][j]);
        }
        __syncthreads();
    }
#pragma unroll
    for (int i = 0; i < 4; i++) {
        int gm = m0 + ty * 4 + i;
#pragma unroll
        for (int j = 0; j < 4; j++) {
            int gn = n0 + tx * 4 + j;
            if (gn < G3) Gi[(size_t)gm * G3 + gn] = acc[i][j] + bih[gn];
        }
    }
}

// ---------------- persistent merged enc+dec GRU scan, single-XCD, L2-coherent exchange ----------------
// 256 WGs launched; first XCD to collect NB tickets wins; its first NB WGs work, rest exit.
// Poll: lane tid<250 spins on its 2 tagged pairs via one dwordx4 sc0 load -> LDS h_s[500].
// FMA: g=tid/25 (6 rows), s=tid%25 (k-segment of 20), W held in 120 VGPRs/lane.
__global__ __launch_bounds__(256, 1) void k_gru2(
    const float* __restrict__ eWhh, const float* __restrict__ ebhh,
    const float* __restrict__ GiE,
    const float* __restrict__ dWhh, const float* __restrict__ dbhh,
    const float* __restrict__ GiD,
    const float* __restrict__ h0, unsigned long long* hbuf, int* claim,
    float* __restrict__ ench_out, float* __restrict__ dechs)
{
    __shared__ __align__(16) float h_s[H];
    __shared__ float p_s[ROWS * 26];   // partials, stride 26 breaks bank conflicts
    __shared__ float gh_s[ROWS];
    __shared__ int wg_s;
    const int tid = threadIdx.x;

    // ---- claim a worker slot on the winning XCD ----
    if (tid == 0) {
        unsigned xcc;
        asm volatile("s_getreg_b32 %0, hwreg(HW_REG_XCC_ID)" : "=s"(xcc));
        int slot = -1;
        int ticket = atomicAdd(claim + xcc, 1);            // device-scope
        if (ticket < NB) {
            if (ticket == NB - 1) atomicCAS(claim + 8, -1, (int)xcc);
            int w;
            do { w = __hip_atomic_load(claim + 8, __ATOMIC_RELAXED,
                                       __HIP_MEMORY_SCOPE_AGENT); } while (w < 0);
            if (w == (int)xcc) slot = ticket;
        }
        wg_s = slot;
    }
    __syncthreads();
    const int wg = wg_s;
    if (wg < 0) return;                                    // non-worker WG

    const int g = tid / 25;            // 0..9  (tid<250)
    const int s = tid - g * 25;        // 0..24
    const int slc = tid / 10;          // poll: pairs 2*tid, 2*tid+1
    const int e0  = 2 * (tid - slc * 10);
    const int j0 = wg * HSL;

    // ---- preload encoder W rows into registers (120 VGPRs/lane) ----
    float wreg[6][20];
    if (tid < 250) {
#pragma unroll
        for (int r = 0; r < 6; ++r) {
            const int rl = g * 6 + r;
            const int gate = rl / 20, jl = rl - gate * 20;
            const float* wr = eWhh + (size_t)(gate * 500 + j0 + jl) * H + s * 20;
#pragma unroll
            for (int c = 0; c < 5; ++c)
                *(float4*)&wreg[r][c * 4] = *(const float4*)(wr + c * 4);
        }
    }
    float bb = 0.f;
    if (tid < ROWS) {
        const int gate = tid / 20, jl = tid - gate * 20;
        bb = ebhh[gate * 500 + j0 + jl];
    }
    float hown = (tid < HSL) ? h0[j0 + tid] : 0.f;

    // ---- prestage h0 into buf1 with tag 1 ----
    if (tid < HSL)
        st8_sc0(hbuf + 800 + wg * 32 + tid,
                ((unsigned long long)1u << 32) | (unsigned)__float_as_uint(hown));

    for (int t = 0; t < 2 * SEQ; ++t) {
        if (t == SEQ) {                // switch to decoder weights; h carries over in regs
            if (tid < 250) {
#pragma unroll
                for (int r = 0; r < 6; ++r) {
                    const int rl = g * 6 + r;
                    const int gate = rl / 20, jl = rl - gate * 20;
                    const float* wr = dWhh + (size_t)(gate * 500 + j0 + jl) * H + s * 20;
#pragma unroll
                    for (int c = 0; c < 5; ++c)
                        *(float4*)&wreg[r][c * 4] = *(const float4*)(wr + c * 4);
                }
            }
            if (tid < ROWS) {
                const int gate = tid / 20, jl = tid - gate * 20;
                bb = dbhh[gate * 500 + j0 + jl];
            }
        }
        const unsigned want = (unsigned)(t + 1);
        const int rb = (t + 1) & 1;                        // read buffer
        // Gi prefetch (long-latency, overlaps the poll)
        float ir = 0.f, iz = 0.f, inn = 0.f;
        if (tid < HSL) {
            const float* gi = (t < SEQ ? GiE + (size_t)t * G3
                                       : GiD + (size_t)(t - SEQ) * G3) + j0 + tid;
            ir = gi[0]; iz = gi[500]; inn = gi[1000];
        }
        // ---- poll own 2 pairs (one 16B sc0 load) until tags match ----
        if (tid < 250) {
            const unsigned long long* pa = hbuf + rb * 800 + slc * 32 + e0;
            unsigned p0, p1;
            int spin = 0;
            for (;;) {
                u32x4 v = ld16_sc0(pa);
                if (v[1] == want && v[3] == want) { p0 = v[0]; p1 = v[2]; break; }
                if (++spin > 48) {     // safety: guaranteed-coherent fallback path
                    unsigned long long a = __hip_atomic_load(pa, __ATOMIC_RELAXED,
                                                             __HIP_MEMORY_SCOPE_AGENT);
                    unsigned long long b = __hip_atomic_load(pa + 1, __ATOMIC_RELAXED,
                                                             __HIP_MEMORY_SCOPE_AGENT);
                    if ((unsigned)(a >> 32) == want && (unsigned)(b >> 32) == want) {
                        p0 = (unsigned)a; p1 = (unsigned)b; break;
                    }
                }
            }
            h_s[2 * tid]     = __uint_as_float(p0);
            h_s[2 * tid + 1] = __uint_as_float(p1);
        }
        __syncthreads();
        // ---- dot: 120 FMAs, W from registers, h from LDS ----
        if (tid < 250) {
            float hv[20];
#pragma unroll
            for (int c = 0; c < 5; ++c)
                *(float4*)&hv[c * 4] = *(const float4*)&h_s[s * 20 + c * 4];
            float acc[6] = {0.f, 0.f, 0.f, 0.f, 0.f, 0.f};
#pragma unroll
            for (int i = 0; i < 20; ++i)
#pragma unroll
                for (int r = 0; r < 6; ++r) acc[r] = fmaf(wreg[r][i], hv[i], acc[r]);
#pragma unroll
            for (int r = 0; r < 6; ++r) p_s[(g * 6 + r) * 26 + s] = acc[r];
        }
        __syncthreads();
        // ---- row reduction over the 25 k-segments ----
        if (tid < ROWS) {
            float sum = 0.f;
#pragma unroll 5
            for (int i = 0; i < 25; ++i) sum += p_s[tid * 26 + i];
            gh_s[tid] = sum + bb;
        }
        __syncthreads();
        // ---- GRU update for own slice ----
        if (tid < HSL) {
            const int j = j0 + tid;
            const float hr = gh_s[tid], hz = gh_s[HSL + tid], hn = gh_s[2 * HSL + tid];
            const float r = 1.f / (1.f + __expf(-(ir + hr)));
            const float z = 1.f / (1.f + __expf(-(iz + hz)));
            const float n = tanhf(inn + r * hn);
            const float hnew = (1.f - z) * n + z * hown;
            hown = hnew;
            st8_sc0(hbuf + (t & 1) * 800 + wg * 32 + tid,
                    ((unsigned long long)(unsigned)(t + 2) << 32) |
                    (unsigned)__float_as_uint(hnew));
            if (t == SEQ - 1) ench_out[j] = hnew;          // encoder final hidden -> out+1
            if (t >= SEQ) dechs[(size_t)(t - SEQ) * H + j] = hnew;
        }
        // h_s rewrite next iter is safe: writers passed B2 (all h_s readers done)
    }
}

// ---------------- logits GEMM with fused sum-exp / argmax partials ----------------
#define LG_BM 128
#define LG_BN 128
#define LG_BK 20
__global__ __launch_bounds__(256) void k_logits(
    const float* __restrict__ A, const float* __restrict__ Bw,
    const float* __restrict__ bias,
    float* __restrict__ S_part, unsigned long long* __restrict__ P_part)
{
    __shared__ __align__(16) float As[LG_BK * LG_BM];
    __shared__ __align__(16) float Bs[LG_BK * LG_BN];
    const int tid = threadIdx.x;
    const int bx = blockIdx.x;
    const int n0 = bx * LG_BN;
    const int m0 = blockIdx.y * LG_BM;
    const int tx = tid & 15, ty = tid >> 4;
    float acc[8][8] = {};
    for (int k0 = 0; k0 < H; k0 += LG_BK) {
        for (int x = tid; x < LG_BM * LG_BK; x += 256) {
            int m = x / LG_BK, k = x - m * LG_BK;
            As[k * LG_BM + m] = A[(size_t)(m0 + m) * H + k0 + k];
        }
        for (int x = tid; x < LG_BN * LG_BK; x += 256) {
            int n = x / LG_BK, k = x - n * LG_BK;
            int gn = n0 + n;
            Bs[k * LG_BN + n] = (gn < V) ? Bw[(size_t)gn * H + k0 + k] : 0.f;
        }
        __syncthreads();
#pragma unroll 5
        for (int kk = 0; kk < LG_BK; ++kk) {
            float a[8], b[8];
            *(float4*)&a[0] = *(const float4*)&As[kk * LG_BM + ty * 8];
            *(float4*)&a[4] = *(const float4*)&As[kk * LG_BM + ty * 8 + 4];
            *(float4*)&b[0] = *(const float4*)&Bs[kk * LG_BN + tx * 8];
            *(float4*)&b[4] = *(const float4*)&Bs[kk * LG_BN + tx * 8 + 4];
#pragma unroll
            for (int i = 0; i < 8; i++)
#pragma unroll
                for (int j = 0; j < 8; j++) acc[i][j] = fmaf(a[i], b[j], acc[i][j]);
        }
        __syncthreads();
    }
    float bcol[8]; int gncol[8]; bool bval[8];
#pragma unroll
    for (int j = 0; j < 8; j++) {
        int gn = n0 + tx * 8 + j;
        gncol[j] = gn; bval[j] = gn < V; bcol[j] = bval[j] ? bias[gn] : 0.f;
    }
#pragma unroll
    for (int i = 0; i < 8; i++) {
        int gm = m0 + ty * 8 + i;
        float mx = -3.4e38f; unsigned mi = 0; float se = 0.f;
#pragma unroll
        for (int j = 0; j < 8; j++) {
            if (bval[j]) {
                float l = acc[i][j] + bcol[j];
                se += __expf(l);
                if (l > mx) { mx = l; mi = (unsigned)gncol[j]; }
            }
        }
        unsigned u = __float_as_uint(mx);
        unsigned key = (u & 0x80000000u) ? ~u : (u | 0x80000000u);
        unsigned long long pk = ((unsigned long long)key << 32) |
                                (unsigned long long)(0xFFFFFFFFu - mi);
#pragma unroll
        for (int off = 1; off < 16; off <<= 1) {
            unsigned long long pk2 = __shfl_xor(pk, off);
            se += __shfl_xor(se, off);
            if (pk2 > pk) pk = pk2;
        }
        if (tx == 0) {
            S_part[(size_t)gm * NT + bx] = se;
            P_part[(size_t)gm * NT + bx] = pk;
        }
    }
}

__global__ __launch_bounds__(128) void k_reduce_rows(
    const float* __restrict__ S_part, const unsigned long long* __restrict__ P_part,
    float* __restrict__ Sfin, float* __restrict__ out_argmax)
{
    const int row = blockIdx.x, tid = threadIdx.x;
    float s = 0.f; unsigned long long p = 0ull;
    for (int i = tid; i < NT; i += 128) {
        s += S_part[(size_t)row * NT + i];
        unsigned long long q = P_part[(size_t)row * NT + i];
        if (q > p) p = q;
    }
#pragma unroll
    for (int off = 1; off < 64; off <<= 1) {
        s += __shfl_xor(s, off);
        unsigned long long q = __shfl_xor(p, off);
        if (q > p) p = q;
    }
    __shared__ float s2[2];
    __shared__ unsigned long long p2[2];
    if ((tid & 63) == 0) { s2[tid >> 6] = s; p2[tid >> 6] = p; }
    __syncthreads();
    if (tid == 0) {
        s = s2[0] + s2[1];
        p = p2[0] > p2[1] ? p2[0] : p2[1];
        Sfin[row] = s;
        unsigned idx = 0xFFFFFFFFu - (unsigned)(p & 0xFFFFFFFFull);
        out_argmax[row] = (float)idx;
    }
}

__global__ __launch_bounds__(64) void k_ltgt(
    const float* __restrict__ A, const float* __restrict__ Bw,
    const float* __restrict__ bias, const int* __restrict__ tgt,
    float* __restrict__ ltgt)
{
    const int row = blockIdx.x, lane = threadIdx.x;
    const int tok = tgt[row];
    const float* a = A + (size_t)row * H;
    const float* b = Bw + (size_t)tok * H;
    float s = 0.f;
    for (int k = lane; k < H; k += 64) s = fmaf(a[k], b[k], s);
#pragma unroll
    for (int off = 1; off < 64; off <<= 1) s += __shfl_xor(s, off);
    if (lane == 0) ltgt[row] = s + bias[tok];
}

__global__ __launch_bounds__(512) void k_final(
    const float* __restrict__ Sfin, const float* __restrict__ ltgt, float* __restrict__ d_out)
{
    __shared__ float red[512];
    const int t = threadIdx.x;
    red[t] = logf(Sfin[t]) - ltgt[t];
    __syncthreads();
    for (int s = 256; s > 0; s >>= 1) {
        if (t < s) red[t] += red[t + s];
        __syncthreads();
    }
    if (t == 0) d_out[0] = red[0];
}

extern "C" void kernel_launch(void* const* d_in, const int* in_sizes, int n_in,
                              void* d_out, int out_size, void* d_ws, size_t ws_size,
                              hipStream_t stream) {
    const int*   enc_ids = (const int*)d_in[0];
    const int*   tgt     = (const int*)d_in[1];
    const float* enc_h0  = (const float*)d_in[2];
    const float* enc_emb = (const float*)d_in[3];
    const float* enc_Wih = (const float*)d_in[4];
    const float* enc_Whh = (const float*)d_in[5];
    const float* enc_bih = (const float*)d_in[6];
    const float* enc_bhh = (const float*)d_in[7];
    const float* dec_emb = (const float*)d_in[8];
    const float* dec_Wih = (const float*)d_in[9];
    const float* dec_Whh = (const float*)d_in[10];
    const float* dec_bih = (const float*)d_in[11];
    const float* dec_bhh = (const float*)d_in[12];
    const float* out_W   = (const float*)d_in[13];
    const float* out_b   = (const float*)d_in[14];
    float* out = (float*)d_out;

    char* ws = (char*)d_ws;
    unsigned long long* hbufE = (unsigned long long*)(ws + OFS_HBUF_E);
    int*   claim  = (int*)(ws + OFS_CLAIM);
    float* gi_enc = (float*)(ws + OFS_GI_ENC);
    float* gi_dec = (float*)(ws + OFS_GI_DEC);
    float* dechs  = (float*)(ws + OFS_DECHS);
    float* Spart  = (float*)(ws + OFS_SPART);
    unsigned long long* Ppart = (unsigned long long*)(ws + OFS_PPART);
    float* ltgt   = (float*)(ws + OFS_LTGT);
    float* Sfin   = (float*)(ws + OFS_SFIN);

    k_gi_gemm<<<dim3(24, 8, 2), dim3(256), 0, stream>>>(
        enc_emb, enc_Wih, enc_bih, enc_ids,
        dec_emb, dec_Wih, dec_bih, tgt, gi_enc, gi_dec, claim);
    k_gru2<<<dim3(NWG_LAUNCH), dim3(256), 0, stream>>>(
        enc_Whh, enc_bhh, gi_enc, dec_Whh, dec_bhh, gi_dec,
        enc_h0, hbufE, claim, out + 1, dechs);
    k_ltgt<<<dim3(SEQ), dim3(64), 0, stream>>>(dechs, out_W, out_b, tgt, ltgt);
    k_logits<<<dim3(NT, 4), dim3(256), 0, stream>>>(dechs, out_W, out_b, Spart, Ppart);
    k_reduce_rows<<<dim3(SEQ), dim3(128), 0, stream>>>(Spart, Ppart, Sfin, out + 1 + H);
    k_final<<<dim3(1), dim3(512), 0, stream>>>(Sfin, ltgt, out);
}

// Round 2
// 2337.105 us; speedup vs baseline: 3.7100x; 3.7100x over previous
//
#include <hip/hip_runtime.h>
#include <cstdint>
#include <cstddef>

#define H    500
#define G3   1500
#define SEQ  512
#define V    50000
#define NT   391          // ceil(50000/128)
#define NTILES (NT * 4)

#define NB   25           // GRU workgroups; HSL = 20 h-elements per WG
#define HSL  20
#define ROWS 60           // 3 gates x 20 rows per WG
#define NWORK 487         // logits worker blocks in the fused decoder kernel

// ---------------- workspace layout (bytes) ----------------
static constexpr size_t OFS_HBUF_E = 0;            // [2 bufs][25 slices][32 u64]
static constexpr size_t OFS_HBUF_D = 16384;
static constexpr size_t OFS_ENCH   = 32768;        // 500 f32
static constexpr size_t OFS_TICKET = 49152;        // 1 int
static constexpr size_t OFS_GI_ENC = 65536;        // 512*1500 f32
static constexpr size_t OFS_GI_DEC = OFS_GI_ENC + 3276800;
static constexpr size_t OFS_DECHS  = OFS_GI_DEC + 3276800;   // 512*500 f32
static constexpr size_t OFS_SPART  = OFS_DECHS + 1048576;    // 512*NT f32
static constexpr size_t OFS_PPART  = OFS_SPART + 1048576;    // 512*NT u64
static constexpr size_t OFS_LTGT   = OFS_PPART + 2097152;    // 512 f32
static constexpr size_t OFS_SFIN   = OFS_LTGT + 4096;        // 512 f32

// ---------------- init: zero exchange buffers + ticket ----------------
__global__ __launch_bounds__(256) void k_init(unsigned long long* hbufE,
                                              unsigned long long* hbufD,
                                              int* ticket)
{
    const int tid = threadIdx.x;
    for (int i = tid; i < 1600; i += 256) { hbufE[i] = 0ull; hbufD[i] = 0ull; }
    if (tid == 0) *ticket = 0;
}

// ---------------- input-gate GEMM: Gi = gather(emb)@Wih.T + bih (enc z=0, dec z=1) ----------------
#define GI_BM 64
#define GI_BN 64
#define GI_BK 20
__global__ __launch_bounds__(256) void k_gi_gemm(
    const float* __restrict__ eA, const float* __restrict__ WA,
    const float* __restrict__ bA, const int* __restrict__ tA,
    const float* __restrict__ eB, const float* __restrict__ WB,
    const float* __restrict__ bB, const int* __restrict__ tB,
    float* __restrict__ GiA, float* __restrict__ GiB)
{
    const int dec = blockIdx.z;
    const float* emb = dec ? eB : eA;
    const float* Wih = dec ? WB : WA;
    const float* bih = dec ? bB : bA;
    const int*  toks = dec ? tB : tA;
    float* Gi        = dec ? GiB : GiA;

    __shared__ __align__(16) float As[GI_BK * GI_BM];
    __shared__ __align__(16) float Bs[GI_BK * GI_BN];
    const int tid = threadIdx.x;
    const int n0 = blockIdx.x * GI_BN;
    const int m0 = blockIdx.y * GI_BM;
    const int tx = tid & 15, ty = tid >> 4;
    float acc[4][4] = {};
    for (int k0 = 0; k0 < H; k0 += GI_BK) {
        for (int x = tid; x < 320; x += 256) {        // 64 rows x 5 float4
            int m = x / 5, kq = x - m * 5;
            int gm = m0 + m;
            int tok = dec ? ((gm == 0) ? 0 : toks[gm - 1]) : toks[gm];
            float4 v = *(const float4*)(emb + (size_t)tok * H + k0 + kq * 4);
            if (dec) { v.x = fmaxf(v.x, 0.f); v.y = fmaxf(v.y, 0.f);
                       v.z = fmaxf(v.z, 0.f); v.w = fmaxf(v.w, 0.f); }
            int kb = kq * 4;
            As[(kb + 0) * GI_BM + m] = v.x; As[(kb + 1) * GI_BM + m] = v.y;
            As[(kb + 2) * GI_BM + m] = v.z; As[(kb + 3) * GI_BM + m] = v.w;
        }
        for (int x = tid; x < 320; x += 256) {
            int n = x / 5, kq = x - n * 5;
            int gn = n0 + n;
            float4 v = make_float4(0.f, 0.f, 0.f, 0.f);
            if (gn < G3) v = *(const float4*)(Wih + (size_t)gn * H + k0 + kq * 4);
            int kb = kq * 4;
            Bs[(kb + 0) * GI_BN + n] = v.x; Bs[(kb + 1) * GI_BN + n] = v.y;
            Bs[(kb + 2) * GI_BN + n] = v.z; Bs[(kb + 3) * GI_BN + n] = v.w;
        }
        __syncthreads();
#pragma unroll 5
        for (int kk = 0; kk < GI_BK; ++kk) {
            float a[4], b[4];
            *(float4*)&a[0] = *(const float4*)&As[kk * GI_BM + ty * 4];
            *(float4*)&b[0] = *(const float4*)&Bs[kk * GI_BN + tx * 4];
#pragma unroll
            for (int i = 0; i < 4; i++)
#pragma unroll
                for (int j = 0; j < 4; j++) acc[i][j] = fmaf(a[i], b[j], acc[i][j]);
        }
        __syncthreads();
    }
#pragma unroll
    for (int i = 0; i < 4; i++) {
        int gm = m0 + ty * 4 + i;
#pragma unroll
        for (int j = 0; j < 4; j++) {
            int gn = n0 + tx * 4 + j;
            if (gn < G3) Gi[(size_t)gm * G3 + gn] = acc[i][j] + bih[gn];
        }
    }
}

// ---------------- persistent GRU scan (encoder): tagged-pair dataflow, r0-proven ----------------
__global__ __launch_bounds__(256, 1) void k_gru(
    const float* __restrict__ Whh, const float* __restrict__ bhh,
    const float* __restrict__ Gi, const float* __restrict__ h0,
    unsigned long long* hbuf, float* hfinal, float* douth, int S)
{
    __shared__ __align__(16) float h_s[H];
    __shared__ float p_s[ROWS * 26];   // partials, stride 26 breaks bank conflicts
    __shared__ float gh_s[ROWS];
    const int tid = threadIdx.x;
    const int wg = blockIdx.x;
    const int j0 = wg * HSL;

    const int g = tid / 25;            // 0..9  (tid<250)
    const int s = tid - g * 25;        // 0..24
    const int slc = tid / 10;
    const int e0  = 2 * (tid - slc * 10);

    float wreg[6][20];
    if (tid < 250) {
#pragma unroll
        for (int r = 0; r < 6; ++r) {
            const int rl = g * 6 + r;
            const int gate = rl / 20, jl = rl - gate * 20;
            const float* wr = Whh + (size_t)(gate * 500 + j0 + jl) * H + s * 20;
#pragma unroll
            for (int c = 0; c < 5; ++c)
                *(float4*)&wreg[r][c * 4] = *(const float4*)(wr + c * 4);
        }
    }
    float bb = 0.f;
    if (tid < ROWS) {
        const int gate = tid / 20, jl = tid - gate * 20;
        bb = bhh[gate * 500 + j0 + jl];
    }
    float hown = (tid < HSL) ? h0[j0 + tid] : 0.f;

    if (tid < HSL)
        __hip_atomic_store(hbuf + 800 + wg * 32 + tid,
                           ((unsigned long long)1u << 32) | (unsigned)__float_as_uint(hown),
                           __ATOMIC_RELAXED, __HIP_MEMORY_SCOPE_AGENT);

    for (int t = 0; t < S; ++t) {
        const unsigned want = (unsigned)(t + 1);
        const int rb = (t + 1) & 1;
        float ir = 0.f, iz = 0.f, inn = 0.f;
        if (tid < HSL) {
            const float* gi = Gi + (size_t)t * G3 + j0 + tid;
            ir = gi[0]; iz = gi[500]; inn = gi[1000];
        }
        if (tid < 250) {
            const unsigned long long* pa = hbuf + rb * 800 + slc * 32 + e0;
            unsigned long long v0, v1;
            do {
                v0 = __hip_atomic_load(pa,     __ATOMIC_RELAXED, __HIP_MEMORY_SCOPE_AGENT);
                v1 = __hip_atomic_load(pa + 1, __ATOMIC_RELAXED, __HIP_MEMORY_SCOPE_AGENT);
            } while (((unsigned)(v0 >> 32) != want) || ((unsigned)(v1 >> 32) != want));
            h_s[2 * tid]     = __uint_as_float((unsigned)v0);
            h_s[2 * tid + 1] = __uint_as_float((unsigned)v1);
        }
        __syncthreads();
        if (tid < 250) {
            float hv[20];
#pragma unroll
            for (int c = 0; c < 5; ++c)
                *(float4*)&hv[c * 4] = *(const float4*)&h_s[s * 20 + c * 4];
            float acc[6] = {0.f, 0.f, 0.f, 0.f, 0.f, 0.f};
#pragma unroll
            for (int i = 0; i < 20; ++i)
#pragma unroll
                for (int r = 0; r < 6; ++r) acc[r] = fmaf(wreg[r][i], hv[i], acc[r]);
#pragma unroll
            for (int r = 0; r < 6; ++r) p_s[(g * 6 + r) * 26 + s] = acc[r];
        }
        __syncthreads();
        if (tid < ROWS) {
            float sum = 0.f;
#pragma unroll 5
            for (int i = 0; i < 25; ++i) sum += p_s[tid * 26 + i];
            gh_s[tid] = sum + bb;
        }
        __syncthreads();
        if (tid < HSL) {
            const int j = j0 + tid;
            const float hr = gh_s[tid], hz = gh_s[HSL + tid], hn = gh_s[2 * HSL + tid];
            const float r = 1.f / (1.f + __expf(-(ir + hr)));
            const float z = 1.f / (1.f + __expf(-(iz + hz)));
            const float n = tanhf(inn + r * hn);
            const float hnew = (1.f - z) * n + z * hown;
            hown = hnew;
            __hip_atomic_store(hbuf + (t & 1) * 800 + wg * 32 + tid,
                               ((unsigned long long)(unsigned)(t + 2) << 32) |
                               (unsigned)__float_as_uint(hnew),
                               __ATOMIC_RELAXED, __HIP_MEMORY_SCOPE_AGENT);
            if (t == S - 1) {
                if (hfinal) hfinal[j] = hnew;
                if (douth)  douth[j]  = hnew;
            }
        }
    }
}

// ---------------- fused decoder: 25 GRU blocks + 487 persistent logits workers ----------------
#define LG_BM 128
#define LG_BN 128
#define LG_BK 20
__global__ __launch_bounds__(256, 1) void k_dec_fused(
    const float* __restrict__ Whh, const float* __restrict__ bhh,
    const float* __restrict__ Gi,  const float* __restrict__ h0,
    unsigned long long* hbuf, float* __restrict__ dechs,
    const float* __restrict__ outW, const float* __restrict__ outb,
    float* __restrict__ S_part, unsigned long long* __restrict__ P_part,
    int* ticket)
{
    const int tid = threadIdx.x;

    if (blockIdx.x < NB) {
        // ================= GRU producer (r0-proven structure) =================
        __builtin_amdgcn_s_setprio(2);     // keep cadence despite co-resident worker FMA waves
        __shared__ __align__(16) float h_s[H];
        __shared__ float p_s[ROWS * 26];
        __shared__ float gh_s[ROWS];
        const int wg = blockIdx.x;
        const int j0 = wg * HSL;
        const int g = tid / 25;
        const int s = tid - g * 25;
        const int slc = tid / 10;
        const int e0  = 2 * (tid - slc * 10);

        float wreg[6][20];
        if (tid < 250) {
#pragma unroll
            for (int r = 0; r < 6; ++r) {
                const int rl = g * 6 + r;
                const int gate = rl / 20, jl = rl - gate * 20;
                const float* wr = Whh + (size_t)(gate * 500 + j0 + jl) * H + s * 20;
#pragma unroll
                for (int c = 0; c < 5; ++c)
                    *(float4*)&wreg[r][c * 4] = *(const float4*)(wr + c * 4);
            }
        }
        float bb = 0.f;
        if (tid < ROWS) {
            const int gate = tid / 20, jl = tid - gate * 20;
            bb = bhh[gate * 500 + j0 + jl];
        }
        float hown = (tid < HSL) ? h0[j0 + tid] : 0.f;

        if (tid < HSL)
            __hip_atomic_store(hbuf + 800 + wg * 32 + tid,
                               ((unsigned long long)1u << 32) | (unsigned)__float_as_uint(hown),
                               __ATOMIC_RELAXED, __HIP_MEMORY_SCOPE_AGENT);

        for (int t = 0; t < SEQ; ++t) {
            const unsigned want = (unsigned)(t + 1);
            const int rb = (t + 1) & 1;
            float ir = 0.f, iz = 0.f, inn = 0.f;
            if (tid < HSL) {
                const float* gi = Gi + (size_t)t * G3 + j0 + tid;
                ir = gi[0]; iz = gi[500]; inn = gi[1000];
            }
            if (tid < 250) {
                const unsigned long long* pa = hbuf + rb * 800 + slc * 32 + e0;
                unsigned long long v0, v1;
                do {
                    v0 = __hip_atomic_load(pa,     __ATOMIC_RELAXED, __HIP_MEMORY_SCOPE_AGENT);
                    v1 = __hip_atomic_load(pa + 1, __ATOMIC_RELAXED, __HIP_MEMORY_SCOPE_AGENT);
                } while (((unsigned)(v0 >> 32) != want) || ((unsigned)(v1 >> 32) != want));
                h_s[2 * tid]     = __uint_as_float((unsigned)v0);
                h_s[2 * tid + 1] = __uint_as_float((unsigned)v1);
            }
            __syncthreads();
            if (tid < 250) {
                float hv[20];
#pragma unroll
                for (int c = 0; c < 5; ++c)
                    *(float4*)&hv[c * 4] = *(const float4*)&h_s[s * 20 + c * 4];
                float acc[6] = {0.f, 0.f, 0.f, 0.f, 0.f, 0.f};
#pragma unroll
                for (int i = 0; i < 20; ++i)
#pragma unroll
                    for (int r = 0; r < 6; ++r) acc[r] = fmaf(wreg[r][i], hv[i], acc[r]);
#pragma unroll
                for (int r = 0; r < 6; ++r) p_s[(g * 6 + r) * 26 + s] = acc[r];
            }
            __syncthreads();
            if (tid < ROWS) {
                float sum = 0.f;
#pragma unroll 5
                for (int i = 0; i < 25; ++i) sum += p_s[tid * 26 + i];
                gh_s[tid] = sum + bb;
            }
            __syncthreads();
            if (tid < HSL) {
                const int j = j0 + tid;
                const float hr = gh_s[tid], hz = gh_s[HSL + tid], hn = gh_s[2 * HSL + tid];
                const float r = 1.f / (1.f + __expf(-(ir + hr)));
                const float z = 1.f / (1.f + __expf(-(iz + hz)));
                const float n = tanhf(inn + r * hn);
                const float hnew = (1.f - z) * n + z * hown;
                hown = hnew;
                // dechs must be agent-visible: cross-XCD workers read it
                __hip_atomic_store(&dechs[(size_t)t * H + j], hnew,
                                   __ATOMIC_RELAXED, __HIP_MEMORY_SCOPE_AGENT);
                const unsigned long long w =
                    ((unsigned long long)(unsigned)(t + 2) << 32) |
                    (unsigned)__float_as_uint(hnew);
                if ((t & 127) == 127)  // drain dechs to coherence point at 128-row epochs
                    __hip_atomic_store(hbuf + (t & 1) * 800 + wg * 32 + tid, w,
                                       __ATOMIC_RELEASE, __HIP_MEMORY_SCOPE_AGENT);
                else
                    __hip_atomic_store(hbuf + (t & 1) * 800 + wg * 32 + tid, w,
                                       __ATOMIC_RELAXED, __HIP_MEMORY_SCOPE_AGENT);
            }
        }
        return;
    }

    // ================= persistent logits worker =================
    __shared__ __align__(16) float As[LG_BK * LG_BM];
    __shared__ __align__(16) float Bs[LG_BK * LG_BN];
    __shared__ int go;

    for (;;) {
        __syncthreads();
        if (tid == 0) go = atomicAdd(ticket, 1);
        __syncthreads();
        const int tk = go;
        if (tk >= NTILES) return;
        const int by = tk / NT, bx = tk - by * NT;
        const int n0 = bx * LG_BN;
        const int m0 = by * LG_BM;

        // ---- wait until decoder rows [0, m0+128) are published & drained ----
        // release at t=127/255/383/511 (all odd -> buf1); any buf1 tag >= m0+129
        // from a lane implies that lane's dechs stores through row m0+127 are visible.
        const unsigned T_need = (unsigned)(m0 + 129);
        if (tid < 64) {
            for (;;) {
                unsigned mn = 0xFFFFFFFFu;
                for (int i = tid; i < 500; i += 64) {
                    const int sl = i / 20, j = i - sl * 20;
                    unsigned long long w = __hip_atomic_load(
                        hbuf + 800 + sl * 32 + j,
                        __ATOMIC_RELAXED, __HIP_MEMORY_SCOPE_AGENT);
                    unsigned tg = (unsigned)(w >> 32);
                    mn = mn < tg ? mn : tg;
                }
#pragma unroll
                for (int off = 32; off; off >>= 1) {
                    unsigned o = __shfl_xor(mn, off);
                    mn = mn < o ? mn : o;
                }
                if (mn >= T_need) break;
                __builtin_amdgcn_s_sleep(32);   // ~2k cycles backoff: keep LLC lines cool
            }
        }
        __syncthreads();
        __threadfence();                        // acquire: invalidate stale L1/L2 lines

        // ---- 128x128 logits tile with fused sum-exp / argmax partials ----
        const int tx = tid & 15, ty = tid >> 4;
        float acc[8][8] = {};
        for (int k0 = 0; k0 < H; k0 += LG_BK) {
            for (int x = tid; x < 640; x += 256) {      // 128 rows x 5 float4
                int m = x / 5, kq = x - m * 5;
                float4 v = *(const float4*)(dechs + (size_t)(m0 + m) * H + k0 + kq * 4);
                int kb = kq * 4;
                As[(kb + 0) * LG_BM + m] = v.x; As[(kb + 1) * LG_BM + m] = v.y;
                As[(kb + 2) * LG_BM + m] = v.z; As[(kb + 3) * LG_BM + m] = v.w;
            }
            for (int x = tid; x < 640; x += 256) {
                int n = x / 5, kq = x - n * 5;
                int gn = n0 + n;
                float4 v = make_float4(0.f, 0.f, 0.f, 0.f);
                if (gn < V) v = *(const float4*)(outW + (size_t)gn * H + k0 + kq * 4);
                int kb = kq * 4;
                Bs[(kb + 0) * LG_BN + n] = v.x; Bs[(kb + 1) * LG_BN + n] = v.y;
                Bs[(kb + 2) * LG_BN + n] = v.z; Bs[(kb + 3) * LG_BN + n] = v.w;
            }
            __syncthreads();
#pragma unroll 5
            for (int kk = 0; kk < LG_BK; ++kk) {
                float a[8], b[8];
                *(float4*)&a[0] = *(const float4*)&As[kk * LG_BM + ty * 8];
                *(float4*)&a[4] = *(const float4*)&As[kk * LG_BM + ty * 8 + 4];
                *(float4*)&b[0] = *(const float4*)&Bs[kk * LG_BN + tx * 8];
                *(float4*)&b[4] = *(const float4*)&Bs[kk * LG_BN + tx * 8 + 4];
#pragma unroll
                for (int i = 0; i < 8; i++)
#pragma unroll
                    for (int j = 0; j < 8; j++) acc[i][j] = fmaf(a[i], b[j], acc[i][j]);
            }
            __syncthreads();
        }
        float bcol[8]; int gncol[8]; bool bval[8];
#pragma unroll
        for (int j = 0; j < 8; j++) {
            int gn = n0 + tx * 8 + j;
            gncol[j] = gn; bval[j] = gn < V; bcol[j] = bval[j] ? outb[gn] : 0.f;
        }
#pragma unroll
        for (int i = 0; i < 8; i++) {
            int gm = m0 + ty * 8 + i;
            float mx = -3.4e38f; unsigned mi = 0; float se = 0.f;
#pragma unroll
            for (int j = 0; j < 8; j++) {
                if (bval[j]) {
                    float l = acc[i][j] + bcol[j];
                    se += __expf(l);
                    if (l > mx) { mx = l; mi = (unsigned)gncol[j]; }
                }
            }
            unsigned u = __float_as_uint(mx);
            unsigned key = (u & 0x80000000u) ? ~u : (u | 0x80000000u);
            unsigned long long pk = ((unsigned long long)key << 32) |
                                    (unsigned long long)(0xFFFFFFFFu - mi);
#pragma unroll
            for (int off = 1; off < 16; off <<= 1) {
                unsigned long long pk2 = __shfl_xor(pk, off);
                se += __shfl_xor(se, off);
                if (pk2 > pk) pk = pk2;
            }
            if (tx == 0) {
                S_part[(size_t)gm * NT + bx] = se;
                P_part[(size_t)gm * NT + bx] = pk;
            }
        }
    }
}

__global__ __launch_bounds__(128) void k_reduce_rows(
    const float* __restrict__ S_part, const unsigned long long* __restrict__ P_part,
    float* __restrict__ Sfin, float* __restrict__ out_argmax)
{
    const int row = blockIdx.x, tid = threadIdx.x;
    float s = 0.f; unsigned long long p = 0ull;
    for (int i = tid; i < NT; i += 128) {
        s += S_part[(size_t)row * NT + i];
        unsigned long long q = P_part[(size_t)row * NT + i];
        if (q > p) p = q;
    }
#pragma unroll
    for (int off = 1; off < 64; off <<= 1) {
        s += __shfl_xor(s, off);
        unsigned long long q = __shfl_xor(p, off);
        if (q > p) p = q;
    }
    __shared__ float s2[2];
    __shared__ unsigned long long p2[2];
    if ((tid & 63) == 0) { s2[tid >> 6] = s; p2[tid >> 6] = p; }
    __syncthreads();
    if (tid == 0) {
        s = s2[0] + s2[1];
        p = p2[0] > p2[1] ? p2[0] : p2[1];
        Sfin[row] = s;
        unsigned idx = 0xFFFFFFFFu - (unsigned)(p & 0xFFFFFFFFull);
        out_argmax[row] = (float)idx;
    }
}

__global__ __launch_bounds__(64) void k_ltgt(
    const float* __restrict__ A, const float* __restrict__ Bw,
    const float* __restrict__ bias, const int* __restrict__ tgt,
    float* __restrict__ ltgt)
{
    const int row = blockIdx.x, lane = threadIdx.x;
    const int tok = tgt[row];
    const float* a = A + (size_t)row * H;
    const float* b = Bw + (size_t)tok * H;
    float s = 0.f;
    for (int k = lane; k < H; k += 64) s = fmaf(a[k], b[k], s);
#pragma unroll
    for (int off = 1; off < 64; off <<= 1) s += __shfl_xor(s, off);
    if (lane == 0) ltgt[row] = s + bias[tok];
}

__global__ __launch_bounds__(512) void k_final(
    const float* __restrict__ Sfin, const float* __restrict__ ltgt, float* __restrict__ d_out)
{
    __shared__ float red[512];
    const int t = threadIdx.x;
    red[t] = logf(Sfin[t]) - ltgt[t];
    __syncthreads();
    for (int s = 256; s > 0; s >>= 1) {
        if (t < s) red[t] += red[t + s];
        __syncthreads();
    }
    if (t == 0) d_out[0] = red[0];
}

extern "C" void kernel_launch(void* const* d_in, const int* in_sizes, int n_in,
                              void* d_out, int out_size, void* d_ws, size_t ws_size,
                              hipStream_t stream) {
    const int*   enc_ids = (const int*)d_in[0];
    const int*   tgt     = (const int*)d_in[1];
    const float* enc_h0  = (const float*)d_in[2];
    const float* enc_emb = (const float*)d_in[3];
    const float* enc_Wih = (const float*)d_in[4];
    const float* enc_Whh = (const float*)d_in[5];
    const float* enc_bih = (const float*)d_in[6];
    const float* enc_bhh = (const float*)d_in[7];
    const float* dec_emb = (const float*)d_in[8];
    const float* dec_Wih = (const float*)d_in[9];
    const float* dec_Whh = (const float*)d_in[10];
    const float* dec_bih = (const float*)d_in[11];
    const float* dec_bhh = (const float*)d_in[12];
    const float* out_W   = (const float*)d_in[13];
    const float* out_b   = (const float*)d_in[14];
    float* out = (float*)d_out;

    char* ws = (char*)d_ws;
    unsigned long long* hbufE = (unsigned long long*)(ws + OFS_HBUF_E);
    unsigned long long* hbufD = (unsigned long long*)(ws + OFS_HBUF_D);
    float* ench   = (float*)(ws + OFS_ENCH);
    int*   ticket = (int*)(ws + OFS_TICKET);
    float* gi_enc = (float*)(ws + OFS_GI_ENC);
    float* gi_dec = (float*)(ws + OFS_GI_DEC);
    float* dechs  = (float*)(ws + OFS_DECHS);
    float* Spart  = (float*)(ws + OFS_SPART);
    unsigned long long* Ppart = (unsigned long long*)(ws + OFS_PPART);
    float* ltgt   = (float*)(ws + OFS_LTGT);
    float* Sfin   = (float*)(ws + OFS_SFIN);

    k_init<<<dim3(1), dim3(256), 0, stream>>>(hbufE, hbufD, ticket);
    k_gi_gemm<<<dim3(24, 8, 2), dim3(256), 0, stream>>>(
        enc_emb, enc_Wih, enc_bih, enc_ids,
        dec_emb, dec_Wih, dec_bih, tgt, gi_enc, gi_dec);
    k_gru<<<dim3(NB), dim3(256), 0, stream>>>(enc_Whh, enc_bhh, gi_enc, enc_h0,
                                              hbufE, ench, out + 1, SEQ);
    k_dec_fused<<<dim3(NB + NWORK), dim3(256), 0, stream>>>(
        dec_Whh, dec_bhh, gi_dec, ench, hbufD, dechs,
        out_W, out_b, Spart, Ppart, ticket);
    k_ltgt<<<dim3(SEQ), dim3(64), 0, stream>>>(dechs, out_W, out_b, tgt, ltgt);
    k_reduce_rows<<<dim3(SEQ), dim3(128), 0, stream>>>(Spart, Ppart, Sfin, out + 1 + H);
    k_final<<<dim3(1), dim3(512), 0, stream>>>(Sfin, ltgt, out);
}